// Round 24
// baseline (226.461 us; speedup 1.0000x reference)
//
#include <hip/hip_runtime.h>

#define NN   100000
#define NE   1600000
#define NL   200000
#define NBUK 782      // coarse buckets of 128 nodes (dst>>7)
#define CAPT 2560     // per-bucket capacity; E=2046, sigma~45 -> 11 sigma margin

#define BIN_BLOCKS  160    // two-pass binning blocks
#define TILE        10240  // edges per bin block (160*10240 >= NE)
#define CEMB_BLOCKS 400    // emb->bf16 grid-stride blocks
#define CW_BLOCKS   32     // 128*128 elems / 512

typedef __attribute__((ext_vector_type(4))) float f32x4;
typedef __attribute__((ext_vector_type(8))) short s16x8;
typedef __attribute__((ext_vector_type(4))) unsigned short us4;

__device__ __forceinline__ unsigned short f2bf(float f) {
    unsigned u = __float_as_uint(f);
    u += 0x7FFFu + ((u >> 16) & 1u);   // RNE
    return (unsigned short)(u >> 16);
}
__device__ __forceinline__ float bf2f(unsigned short h) {
    return __uint_as_float(((unsigned)h) << 16);
}
__device__ __forceinline__ float bf_lo(unsigned v) {         // low bf16 of packed pair
    return __uint_as_float(v << 16);
}
__device__ __forceinline__ float bf_hi(unsigned v) {         // high bf16 of packed pair
    return __uint_as_float(v & 0xFFFF0000u);
}

// ---- merged prep: [0,160) two-pass bin; [160,560) emb->bf16; [560,592) w-cat ----
__global__ void __launch_bounds__(512) prep_kernel(
        const int* __restrict__ src, const int* __restrict__ dst,
        int* __restrict__ gcur, int* __restrict__ tmp,
        const float* __restrict__ emb, unsigned short* __restrict__ embb,
        const float* __restrict__ w1l, const float* __restrict__ w1r,
        const float* __restrict__ w2l, const float* __restrict__ w2r,
        unsigned short* __restrict__ w1cat, unsigned short* __restrict__ w2cat) {
    const int bid = blockIdx.x;
    const int tid = threadIdx.x;

    if (bid < BIN_BLOCKS) {
        __shared__ int hist[NBUK];
        __shared__ int base[NBUK];
        const int t0  = bid * TILE;
        const int end = min(t0 + TILE, NE);

        for (int k = tid; k < NBUK; k += 512) hist[k] = 0;
        __syncthreads();

        for (int i = t0 + tid; i < end; i += 512)
            atomicAdd(&hist[__builtin_nontemporal_load(dst + i) >> 7], 1);
        __syncthreads();

        for (int k = tid; k < NBUK; k += 512) {
            int c = hist[k];
            base[k] = c ? atomicAdd(&gcur[k], c) : 0;
        }
        __syncthreads();

        for (int i = t0 + tid; i < end; i += 512) {
            int d = __builtin_nontemporal_load(dst + i);
            int s = __builtin_nontemporal_load(src + i);
            int b = d >> 7;
            int pos = atomicAdd(&base[b], 1);
            if (pos < CAPT) tmp[b * CAPT + pos] = ((d & 127) << 17) | s;
        }
    } else if (bid < BIN_BLOCKS + CEMB_BLOCKS) {
        for (int i = (bid - BIN_BLOCKS) * 512 + tid; i < NN * 16; i += CEMB_BLOCKS * 512) {
            float4 v = ((const float4*)emb)[i];
            us4 o;
            o.x = f2bf(v.x); o.y = f2bf(v.y); o.z = f2bf(v.z); o.w = f2bf(v.w);
            ((us4*)embb)[i] = o;
        }
    } else {
        int t = (bid - BIN_BLOCKS - CEMB_BLOCKS) * 512 + tid;
        if (t >= 128 * 128) return;
        int o = t >> 7, k = t & 127;
        w1cat[t] = f2bf(k < 64 ? w1l[o * 64 + k] : w1r[o * 64 + (k - 64)]);
        w2cat[t] = f2bf(o < 64 ? w2l[o * 128 + k] : w2r[(o - 64) * 128 + k]);
    }
}

// ------- per-coarse-bucket (128 nodes) agg: micro-CSR -> paired-edge 4B/lane gather ----
// Half-waves own alternate edges; lane handles channel pair (2*(lane&31), +1).
// L1=true : outb[i] = bf16( (1/max(deg,1)) * sum xb[j] )
// L1=false: outb[i] = bf16( (1/max(deg,1)) * sum xb[j] + hzb[i] + bias )
template<bool L1>
__global__ void __launch_bounds__(512) agg_kernel(
        const int* __restrict__ gcur, const int* __restrict__ tmp,
        const unsigned short* __restrict__ xb,
        const unsigned short* __restrict__ hzb, const float* __restrict__ bias,
        unsigned short* __restrict__ outb) {
    __shared__ int scnt[128];
    __shared__ int soff[128];
    __shared__ int scur[128];
    __shared__ int slist[CAPT];

    const int b    = blockIdx.x;
    const int tid  = threadIdx.x;
    const int lane = tid & 63;
    const int wv   = tid >> 6;    // 0..7
    const int half = lane >> 5;   // 0..1: which edge of the pair
    const int ch2  = lane & 31;   // channel pair index

    if (tid < 128) scnt[tid] = 0;
    __syncthreads();

    const int cnt = min(gcur[b], CAPT);
    const int* tb = tmp + b * CAPT;

    for (int i = tid; i < cnt; i += 512)
        atomicAdd(&scnt[tb[i] >> 17], 1);
    __syncthreads();

    if (tid == 0) {
        int acc = 0;
        for (int r = 0; r < 128; ++r) {
            soff[r] = acc;
            scur[r] = acc;
            acc += scnt[r];
        }
    }
    __syncthreads();

    for (int i = tid; i < cnt; i += 512) {
        int p = tb[i];
        int pos = atomicAdd(&scur[p >> 17], 1);
        slist[pos] = p & 0x1FFFF;
    }
    __syncthreads();

    const unsigned* xb32 = (const unsigned*)xb;   // rows of 32 packed bf16-pairs
    float bbx = 0.f, bby = 0.f;
    if (!L1) {
        bbx = bias[2 * ch2];
        bby = bias[2 * ch2 + 1];
    }

    for (int r = wv; r < 128; r += 8) {
        const int node = b * 128 + r;
        if (node >= NN) continue;
        const int s = soff[r];
        const int d = scnt[r];
        float ax = 0.f, ay = 0.f;
        int j = 0;
        // 16 edges per iter: 8 independent 4B loads per lane
        for (; j + 16 <= d; j += 16) {
            int c[8];
#pragma unroll
            for (int k = 0; k < 8; ++k) c[k] = slist[s + j + 2 * k + half];
#pragma unroll
            for (int k = 0; k < 8; ++k) {
                unsigned v = xb32[(size_t)c[k] * 32 + ch2];
                ax += bf_lo(v);
                ay += bf_hi(v);
            }
        }
        if (j + 8 <= d) {
            int c[4];
#pragma unroll
            for (int k = 0; k < 4; ++k) c[k] = slist[s + j + 2 * k + half];
#pragma unroll
            for (int k = 0; k < 4; ++k) {
                unsigned v = xb32[(size_t)c[k] * 32 + ch2];
                ax += bf_lo(v);
                ay += bf_hi(v);
            }
            j += 8;
        }
        for (; j + 2 <= d; j += 2) {
            int c = slist[s + j + half];
            unsigned v = xb32[(size_t)c * 32 + ch2];
            ax += bf_lo(v);
            ay += bf_hi(v);
        }
        if (j < d && half == 0) {   // last odd edge: lower half only
            int c = slist[s + j];
            unsigned v = xb32[(size_t)c * 32 + ch2];
            ax += bf_lo(v);
            ay += bf_hi(v);
        }
        // merge half-wave partials
        ax += __shfl_xor(ax, 32, 64);
        ay += __shfl_xor(ay, 32, 64);

        if (half == 0) {
            const float inv = 1.0f / fmaxf((float)d, 1.0f);
            float ox = ax * inv, oy = ay * inv;
            if (!L1) {
                unsigned hv = ((const unsigned*)hzb)[(size_t)node * 32 + ch2];
                ox += bf_lo(hv) + bbx;
                oy += bf_hi(hv) + bby;
            }
            unsigned pack = (unsigned)f2bf(ox) | ((unsigned)f2bf(oy) << 16);
            ((unsigned*)outb)[(size_t)node * 32 + ch2] = pack;
        }
    }
}

// ---------------- MFMA fused 2-layer GEMM: 128 nodes/block, 4 waves, 0 barriers ------
// GEMM1: h = relu(cat(aggb,embb) @ w1cat^T + b1)  (bf16 A from global, h -> LDS bf16)
// GEMM2: p2b = bf16(h @ w2l^T), hzb = bf16(h @ w2r^T)    (A from LDS, B = w2cat)
// Fragment layouts (mfma_f32_16x16x32_bf16): A: lane holds A[l&15][8*(l>>4)+j];
// B: lane holds B[8*(l>>4)+j][l&15]; C/D: col=lane&15, row=(lane>>4)*4+reg [m89/m91].
__global__ void __launch_bounds__(256) gemm_mfma_kernel(
        const unsigned short* __restrict__ aggb, const unsigned short* __restrict__ embb,
        const unsigned short* __restrict__ w1cat, const float* __restrict__ b1,
        const unsigned short* __restrict__ w2cat,
        unsigned short* __restrict__ p2b, unsigned short* __restrict__ hzb) {
    __shared__ unsigned short h_lds[128 * 136];

    const int tid  = threadIdx.x;
    const int lane = tid & 63;
    const int w    = tid >> 6;
    const int l15  = lane & 15;
    const int lk   = lane >> 4;
    const int n_base = blockIdx.x * 128;
    const int mrow0  = w * 32;

    f32x4 acc[2][8];
#pragma unroll
    for (int mt = 0; mt < 2; ++mt)
#pragma unroll
        for (int nt = 0; nt < 8; ++nt) acc[mt][nt] = (f32x4)(0.f);

    // ================= GEMM 1 =================
#pragma unroll
    for (int ks = 0; ks < 4; ++ks) {
        const int kc = ks * 32 + lk * 8;
        s16x8 a[2];
#pragma unroll
        for (int mt = 0; mt < 2; ++mt) {
            int n = n_base + mrow0 + mt * 16 + l15;
            s16x8 av = (s16x8)(short)0;
            if (n < NN) {
                const unsigned short* ap = (kc < 64)
                    ? (aggb + (size_t)n * 64 + kc)
                    : (embb + (size_t)n * 64 + (kc - 64));
                av = *(const s16x8*)ap;
            }
            a[mt] = av;
        }
#pragma unroll
        for (int nt = 0; nt < 8; ++nt) {
            s16x8 bv = *(const s16x8*)(w1cat + (nt * 16 + l15) * 128 + kc);
            acc[0][nt] = __builtin_amdgcn_mfma_f32_16x16x32_bf16(a[0], bv, acc[0][nt], 0, 0, 0);
            acc[1][nt] = __builtin_amdgcn_mfma_f32_16x16x32_bf16(a[1], bv, acc[1][nt], 0, 0, 0);
        }
    }

    float b1v[8];
#pragma unroll
    for (int nt = 0; nt < 8; ++nt) b1v[nt] = b1[nt * 16 + l15];
#pragma unroll
    for (int mt = 0; mt < 2; ++mt)
#pragma unroll
        for (int nt = 0; nt < 8; ++nt) {
            f32x4 d = acc[mt][nt];
            int o = nt * 16 + l15;
            int r0 = mrow0 + mt * 16 + lk * 4;
#pragma unroll
            for (int j = 0; j < 4; ++j)
                h_lds[(r0 + j) * 136 + o] = f2bf(fmaxf(d[j] + b1v[nt], 0.f));
        }

#pragma unroll
    for (int mt = 0; mt < 2; ++mt)
#pragma unroll
        for (int nt = 0; nt < 8; ++nt) acc[mt][nt] = (f32x4)(0.f);

    // ================= GEMM 2 =================
#pragma unroll
    for (int ks = 0; ks < 4; ++ks) {
        const int kc = ks * 32 + lk * 8;
        s16x8 a[2];
#pragma unroll
        for (int mt = 0; mt < 2; ++mt)
            a[mt] = *(const s16x8*)&h_lds[(mrow0 + mt * 16 + l15) * 136 + kc];
#pragma unroll
        for (int nt = 0; nt < 8; ++nt) {
            s16x8 bv = *(const s16x8*)(w2cat + (nt * 16 + l15) * 128 + kc);
            acc[0][nt] = __builtin_amdgcn_mfma_f32_16x16x32_bf16(a[0], bv, acc[0][nt], 0, 0, 0);
            acc[1][nt] = __builtin_amdgcn_mfma_f32_16x16x32_bf16(a[1], bv, acc[1][nt], 0, 0, 0);
        }
    }

    // epilogue 2: nt<4 -> p2b (bf16), nt>=4 -> hzb (bf16)
#pragma unroll
    for (int mt = 0; mt < 2; ++mt)
#pragma unroll
        for (int nt = 0; nt < 8; ++nt) {
            f32x4 d = acc[mt][nt];
            int o = nt * 16 + l15;
            int r0 = n_base + mrow0 + mt * 16 + lk * 4;
#pragma unroll
            for (int j = 0; j < 4; ++j) {
                int r = r0 + j;
                if (r >= NN) continue;
                if (nt < 4) p2b[(size_t)r * 64 + o] = f2bf(d[j]);
                else        hzb[(size_t)r * 64 + (o - 64)] = f2bf(d[j]);
            }
        }
}

// ---------------- decode (bf16 z): out[k] = dot(z[a[k]], z[b[k]]) ----------------
__global__ void decode_kernel(const int* __restrict__ a, const int* __restrict__ b,
                              const unsigned short* __restrict__ zb, float* __restrict__ out) {
    int t = blockIdx.x * blockDim.x + threadIdx.x;
    int k = t >> 4;
    int q = t & 15;
    if (k >= NL) return;
    int ia = a[k], ib = b[k];
    us4 va = ((const us4*)zb)[ia * 16 + q];
    us4 vb = ((const us4*)zb)[ib * 16 + q];
    float s = bf2f(va.x) * bf2f(vb.x) + bf2f(va.y) * bf2f(vb.y)
            + bf2f(va.z) * bf2f(vb.z) + bf2f(va.w) * bf2f(vb.w);
    s += __shfl_xor(s, 1, 64);
    s += __shfl_xor(s, 2, 64);
    s += __shfl_xor(s, 4, 64);
    s += __shfl_xor(s, 8, 64);
    if (q == 0) __builtin_nontemporal_store(s, out + k);
}

extern "C" void kernel_launch(void* const* d_in, const int* in_sizes, int n_in,
                              void* d_out, int out_size, void* d_ws, size_t ws_size,
                              hipStream_t stream) {
    const float* emb = (const float*)d_in[0];
    const float* w1l = (const float*)d_in[1];
    const float* w1r = (const float*)d_in[2];
    const float* b1  = (const float*)d_in[3];
    const float* w2l = (const float*)d_in[4];
    const float* w2r = (const float*)d_in[5];
    const float* b2  = (const float*)d_in[6];
    const int*   ei  = (const int*)d_in[7];
    const int*   eli = (const int*)d_in[8];
    float* out = (float*)d_out;

    // workspace layout (~73 MB)
    int* gcur = (int*)d_ws;                                   // 1024 ints (782 used)
    int* tmp  = gcur + 1024;                                  // NBUK*CAPT = 2,001,920 ints
    unsigned short* aggb  = (unsigned short*)(tmp + (size_t)NBUK * CAPT);  // NN*64 bf16
    unsigned short* embb  = aggb + (size_t)NN * 64;           // NN*64 bf16
    unsigned short* p2b   = embb + (size_t)NN * 64;           // NN*64 bf16
    unsigned short* zb    = p2b + (size_t)NN * 64;            // NN*64 bf16
    unsigned short* hzb   = zb + (size_t)NN * 64;             // NN*64 bf16
    unsigned short* w1cat = hzb + (size_t)NN * 64;            // 128*128 bf16
    unsigned short* w2cat = w1cat + 128 * 128;                // 128*128 bf16

    const int* src = ei;
    const int* dst = ei + NE;

    hipMemsetAsync(gcur, 0, 1024 * sizeof(int), stream);

    // merged prep: two-pass binning + emb->bf16 + weight concat
    prep_kernel<<<BIN_BLOCKS + CEMB_BLOCKS + CW_BLOCKS, 512, 0, stream>>>(
        src, dst, gcur, tmp, emb, embb, w1l, w1r, w2l, w2r, w1cat, w2cat);

    // layer 1 aggregation (paired-edge bf16 gather): aggb = bf16(mean-gather(embb))
    agg_kernel<true><<<NBUK, 512, 0, stream>>>(gcur, tmp, embb, nullptr, nullptr, aggb);

    // fused MFMA layers: h = relu(cat(agg,emb)@w1cat^T + b1); {p2b, hzb} = h@{w2l,w2r}^T
    const int NT = (NN + 127) / 128;  // 782
    gemm_mfma_kernel<<<NT, 256, 0, stream>>>(aggb, embb, w1cat, b1, w2cat, p2b, hzb);

    // layer 2 aggregation + fuse: zb = bf16(mean-gather(p2b) + hz + b2)
    agg_kernel<false><<<NBUK, 512, 0, stream>>>(gcur, tmp, p2b, hzb, b2, zb);

    // decode
    decode_kernel<<<(NL * 16 + 255) / 256, 256, 0, stream>>>(eli, eli + NL, zb, out);
}

// Round 25
// 196.895 us; speedup vs baseline: 1.1502x; 1.1502x over previous
//
#include <hip/hip_runtime.h>

#define NN   100000
#define NE   1600000
#define NL   200000
#define NBUK 782      // coarse buckets of 128 nodes (dst>>7)
#define CAPT 2560     // per-bucket capacity; E=2046, sigma~45 -> 11 sigma margin

#define BIN_BLOCKS  160    // two-pass binning blocks
#define TILE        10240  // edges per bin block (160*10240 >= NE)
#define CEMB_BLOCKS 400    // emb->bf16 grid-stride blocks
#define CW_BLOCKS   32     // 128*128 elems / 512

typedef __attribute__((ext_vector_type(4))) float f32x4;
typedef __attribute__((ext_vector_type(8))) short s16x8;
typedef __attribute__((ext_vector_type(4))) unsigned short us4;

__device__ __forceinline__ unsigned short f2bf(float f) {
    unsigned u = __float_as_uint(f);
    u += 0x7FFFu + ((u >> 16) & 1u);   // RNE
    return (unsigned short)(u >> 16);
}
__device__ __forceinline__ float bf2f(unsigned short h) {
    return __uint_as_float(((unsigned)h) << 16);
}

// ---- merged prep: [0,160) two-pass bin; [160,560) emb->bf16; [560,592) w-cat ----
__global__ void __launch_bounds__(512) prep_kernel(
        const int* __restrict__ src, const int* __restrict__ dst,
        int* __restrict__ gcur, int* __restrict__ tmp,
        const float* __restrict__ emb, unsigned short* __restrict__ embb,
        const float* __restrict__ w1l, const float* __restrict__ w1r,
        const float* __restrict__ w2l, const float* __restrict__ w2r,
        unsigned short* __restrict__ w1cat, unsigned short* __restrict__ w2cat) {
    const int bid = blockIdx.x;
    const int tid = threadIdx.x;

    if (bid < BIN_BLOCKS) {
        __shared__ int hist[NBUK];
        __shared__ int base[NBUK];
        const int t0  = bid * TILE;
        const int end = min(t0 + TILE, NE);

        for (int k = tid; k < NBUK; k += 512) hist[k] = 0;
        __syncthreads();

        // pass 1: per-tile histogram
        for (int i = t0 + tid; i < end; i += 512)
            atomicAdd(&hist[__builtin_nontemporal_load(dst + i) >> 7], 1);
        __syncthreads();

        // reserve contiguous runs: one global atomic per (block,bucket)
        for (int k = tid; k < NBUK; k += 512) {
            int c = hist[k];
            base[k] = c ? atomicAdd(&gcur[k], c) : 0;
        }
        __syncthreads();

        // pass 2: scatter into reserved runs (contiguous per bucket per block)
        for (int i = t0 + tid; i < end; i += 512) {
            int d = __builtin_nontemporal_load(dst + i);
            int s = __builtin_nontemporal_load(src + i);
            int b = d >> 7;
            int pos = atomicAdd(&base[b], 1);
            if (pos < CAPT) tmp[b * CAPT + pos] = ((d & 127) << 17) | s;
        }
    } else if (bid < BIN_BLOCKS + CEMB_BLOCKS) {
        // ---- emb fp32 -> bf16, grid-stride ----
        for (int i = (bid - BIN_BLOCKS) * 512 + tid; i < NN * 16; i += CEMB_BLOCKS * 512) {
            float4 v = ((const float4*)emb)[i];
            us4 o;
            o.x = f2bf(v.x); o.y = f2bf(v.y); o.z = f2bf(v.z); o.w = f2bf(v.w);
            ((us4*)embb)[i] = o;
        }
    } else {
        // ---- weight concat -> bf16 ----
        int t = (bid - BIN_BLOCKS - CEMB_BLOCKS) * 512 + tid;
        if (t >= 128 * 128) return;
        int o = t >> 7, k = t & 127;
        w1cat[t] = f2bf(k < 64 ? w1l[o * 64 + k] : w1r[o * 64 + (k - 64)]);
        w2cat[t] = f2bf(o < 64 ? w2l[o * 128 + k] : w2r[(o - 64) * 128 + k]);
    }
}

// ------- per-coarse-bucket (128 nodes) agg: micro-CSR from dense list -> reg gather ----
// L1=true : outb[i] = bf16( (1/max(deg,1)) * sum bf2f(xb[j]) )
// L1=false: outb[i] = bf16( (1/max(deg,1)) * sum bf2f(xb[j]) + bf2f(hzb[i]) + bias )
template<bool L1>
__global__ void __launch_bounds__(512) agg_kernel(
        const int* __restrict__ gcur, const int* __restrict__ tmp,
        const unsigned short* __restrict__ xb,
        const unsigned short* __restrict__ hzb, const float* __restrict__ bias,
        unsigned short* __restrict__ outb) {
    __shared__ int scnt[128];
    __shared__ int soff[128];
    __shared__ int scur[128];
    __shared__ int slist[CAPT];   // grouped-by-node src ids (10 KB)

    const int b    = blockIdx.x;
    const int tid  = threadIdx.x;
    const int lane = tid & 63;
    const int wv   = tid >> 6;    // 0..7

    if (tid < 128) scnt[tid] = 0;
    __syncthreads();

    const int cnt = min(gcur[b], CAPT);
    const int* tb = tmp + b * CAPT;

    // phase 1: per-node counts (= degree), coalesced read
    for (int i = tid; i < cnt; i += 512)
        atomicAdd(&scnt[tb[i] >> 17], 1);
    __syncthreads();

    // phase 2: exclusive scan of 128
    if (tid == 0) {
        int acc = 0;
        for (int r = 0; r < 128; ++r) {
            soff[r] = acc;
            scur[r] = acc;
            acc += scnt[r];
        }
    }
    __syncthreads();

    // phase 3: scatter src ids into per-node lists (tb re-read, L2-hot)
    for (int i = tid; i < cnt; i += 512) {
        int p = tb[i];
        int pos = atomicAdd(&scur[p >> 17], 1);
        slist[pos] = p & 0x1FFFF;
    }
    __syncthreads();

    const float bb = L1 ? 0.f : bias[lane];

#define LDX(c) bf2f(xb[(size_t)(c) * 64 + lane])
    for (int r = wv; r < 128; r += 8) {
        const int node = b * 128 + r;
        if (node >= NN) continue;
        const int s = soff[r];
        const int d = scnt[r];
        float acc = 0.f;
        int j = 0;
        for (; j + 8 <= d; j += 8) {
            int c0 = slist[s + j + 0], c1 = slist[s + j + 1];
            int c2 = slist[s + j + 2], c3 = slist[s + j + 3];
            int c4 = slist[s + j + 4], c5 = slist[s + j + 5];
            int c6 = slist[s + j + 6], c7 = slist[s + j + 7];
            float v0 = LDX(c0), v1 = LDX(c1), v2 = LDX(c2), v3 = LDX(c3);
            float v4 = LDX(c4), v5 = LDX(c5), v6 = LDX(c6), v7 = LDX(c7);
            acc += ((v0 + v1) + (v2 + v3)) + ((v4 + v5) + (v6 + v7));
        }
        if (j + 4 <= d) {
            int c0 = slist[s + j + 0], c1 = slist[s + j + 1];
            int c2 = slist[s + j + 2], c3 = slist[s + j + 3];
            float v0 = LDX(c0), v1 = LDX(c1), v2 = LDX(c2), v3 = LDX(c3);
            acc += (v0 + v1) + (v2 + v3);
            j += 4;
        }
        for (; j < d; ++j) acc += LDX(slist[s + j]);

        const float inv = 1.0f / fmaxf((float)d, 1.0f);
        if (L1) {
            outb[(size_t)node * 64 + lane] = f2bf(acc * inv);
        } else {
            outb[(size_t)node * 64 + lane] =
                f2bf(acc * inv + bf2f(hzb[(size_t)node * 64 + lane]) + bb);
        }
    }
#undef LDX
}

// ---------------- MFMA fused 2-layer GEMM: 128 nodes/block, 4 waves, 0 barriers ------
// GEMM1: h = relu(cat(aggb,embb) @ w1cat^T + b1)  (bf16 A from global, h -> LDS bf16)
// GEMM2: p2b = bf16(h @ w2l^T), hzb = bf16(h @ w2r^T)    (A from LDS, B = w2cat)
// Fragment layouts (mfma_f32_16x16x32_bf16): A: lane holds A[l&15][8*(l>>4)+j];
// B: lane holds B[8*(l>>4)+j][l&15]; C/D: col=lane&15, row=(lane>>4)*4+reg [m89/m91].
__global__ void __launch_bounds__(256) gemm_mfma_kernel(
        const unsigned short* __restrict__ aggb, const unsigned short* __restrict__ embb,
        const unsigned short* __restrict__ w1cat, const float* __restrict__ b1,
        const unsigned short* __restrict__ w2cat,
        unsigned short* __restrict__ p2b, unsigned short* __restrict__ hzb) {
    __shared__ unsigned short h_lds[128 * 136];

    const int tid  = threadIdx.x;
    const int lane = tid & 63;
    const int w    = tid >> 6;
    const int l15  = lane & 15;
    const int lk   = lane >> 4;
    const int n_base = blockIdx.x * 128;
    const int mrow0  = w * 32;

    f32x4 acc[2][8];
#pragma unroll
    for (int mt = 0; mt < 2; ++mt)
#pragma unroll
        for (int nt = 0; nt < 8; ++nt) acc[mt][nt] = (f32x4)(0.f);

    // ================= GEMM 1 =================
#pragma unroll
    for (int ks = 0; ks < 4; ++ks) {
        const int kc = ks * 32 + lk * 8;
        s16x8 a[2];
#pragma unroll
        for (int mt = 0; mt < 2; ++mt) {
            int n = n_base + mrow0 + mt * 16 + l15;
            s16x8 av = (s16x8)(short)0;
            if (n < NN) {
                const unsigned short* ap = (kc < 64)
                    ? (aggb + (size_t)n * 64 + kc)
                    : (embb + (size_t)n * 64 + (kc - 64));
                av = *(const s16x8*)ap;
            }
            a[mt] = av;
        }
#pragma unroll
        for (int nt = 0; nt < 8; ++nt) {
            s16x8 bv = *(const s16x8*)(w1cat + (nt * 16 + l15) * 128 + kc);
            acc[0][nt] = __builtin_amdgcn_mfma_f32_16x16x32_bf16(a[0], bv, acc[0][nt], 0, 0, 0);
            acc[1][nt] = __builtin_amdgcn_mfma_f32_16x16x32_bf16(a[1], bv, acc[1][nt], 0, 0, 0);
        }
    }

    // epilogue 1: bias + relu -> h_lds (wave-private rows; no barrier needed)
    float b1v[8];
#pragma unroll
    for (int nt = 0; nt < 8; ++nt) b1v[nt] = b1[nt * 16 + l15];
#pragma unroll
    for (int mt = 0; mt < 2; ++mt)
#pragma unroll
        for (int nt = 0; nt < 8; ++nt) {
            f32x4 d = acc[mt][nt];
            int o = nt * 16 + l15;
            int r0 = mrow0 + mt * 16 + lk * 4;
#pragma unroll
            for (int j = 0; j < 4; ++j)
                h_lds[(r0 + j) * 136 + o] = f2bf(fmaxf(d[j] + b1v[nt], 0.f));
        }

#pragma unroll
    for (int mt = 0; mt < 2; ++mt)
#pragma unroll
        for (int nt = 0; nt < 8; ++nt) acc[mt][nt] = (f32x4)(0.f);

    // ================= GEMM 2 =================
#pragma unroll
    for (int ks = 0; ks < 4; ++ks) {
        const int kc = ks * 32 + lk * 8;
        s16x8 a[2];
#pragma unroll
        for (int mt = 0; mt < 2; ++mt)
            a[mt] = *(const s16x8*)&h_lds[(mrow0 + mt * 16 + l15) * 136 + kc];
#pragma unroll
        for (int nt = 0; nt < 8; ++nt) {
            s16x8 bv = *(const s16x8*)(w2cat + (nt * 16 + l15) * 128 + kc);
            acc[0][nt] = __builtin_amdgcn_mfma_f32_16x16x32_bf16(a[0], bv, acc[0][nt], 0, 0, 0);
            acc[1][nt] = __builtin_amdgcn_mfma_f32_16x16x32_bf16(a[1], bv, acc[1][nt], 0, 0, 0);
        }
    }

    // epilogue 2: nt<4 -> p2b (bf16), nt>=4 -> hzb (bf16)
#pragma unroll
    for (int mt = 0; mt < 2; ++mt)
#pragma unroll
        for (int nt = 0; nt < 8; ++nt) {
            f32x4 d = acc[mt][nt];
            int o = nt * 16 + l15;
            int r0 = n_base + mrow0 + mt * 16 + lk * 4;
#pragma unroll
            for (int j = 0; j < 4; ++j) {
                int r = r0 + j;
                if (r >= NN) continue;
                if (nt < 4) p2b[(size_t)r * 64 + o] = f2bf(d[j]);
                else        hzb[(size_t)r * 64 + (o - 64)] = f2bf(d[j]);
            }
        }
}

// ---------------- decode (bf16 z): out[k] = dot(z[a[k]], z[b[k]]) ----------------
__global__ void decode_kernel(const int* __restrict__ a, const int* __restrict__ b,
                              const unsigned short* __restrict__ zb, float* __restrict__ out) {
    int t = blockIdx.x * blockDim.x + threadIdx.x;
    int k = t >> 4;
    int q = t & 15;
    if (k >= NL) return;
    int ia = a[k], ib = b[k];
    us4 va = ((const us4*)zb)[ia * 16 + q];
    us4 vb = ((const us4*)zb)[ib * 16 + q];
    float s = bf2f(va.x) * bf2f(vb.x) + bf2f(va.y) * bf2f(vb.y)
            + bf2f(va.z) * bf2f(vb.z) + bf2f(va.w) * bf2f(vb.w);
    s += __shfl_xor(s, 1, 64);
    s += __shfl_xor(s, 2, 64);
    s += __shfl_xor(s, 4, 64);
    s += __shfl_xor(s, 8, 64);
    if (q == 0) __builtin_nontemporal_store(s, out + k);
}

extern "C" void kernel_launch(void* const* d_in, const int* in_sizes, int n_in,
                              void* d_out, int out_size, void* d_ws, size_t ws_size,
                              hipStream_t stream) {
    const float* emb = (const float*)d_in[0];
    const float* w1l = (const float*)d_in[1];
    const float* w1r = (const float*)d_in[2];
    const float* b1  = (const float*)d_in[3];
    const float* w2l = (const float*)d_in[4];
    const float* w2r = (const float*)d_in[5];
    const float* b2  = (const float*)d_in[6];
    const int*   ei  = (const int*)d_in[7];
    const int*   eli = (const int*)d_in[8];
    float* out = (float*)d_out;

    // workspace layout (~73 MB)
    int* gcur = (int*)d_ws;                                   // 1024 ints (782 used)
    int* tmp  = gcur + 1024;                                  // NBUK*CAPT = 2,001,920 ints
    unsigned short* aggb  = (unsigned short*)(tmp + (size_t)NBUK * CAPT);  // NN*64 bf16
    unsigned short* embb  = aggb + (size_t)NN * 64;           // NN*64 bf16
    unsigned short* p2b   = embb + (size_t)NN * 64;           // NN*64 bf16
    unsigned short* zb    = p2b + (size_t)NN * 64;            // NN*64 bf16
    unsigned short* hzb   = zb + (size_t)NN * 64;             // NN*64 bf16
    unsigned short* w1cat = hzb + (size_t)NN * 64;            // 128*128 bf16
    unsigned short* w2cat = w1cat + 128 * 128;                // 128*128 bf16

    const int* src = ei;
    const int* dst = ei + NE;

    hipMemsetAsync(gcur, 0, 1024 * sizeof(int), stream);

    // merged prep: two-pass binning + emb->bf16 + weight concat
    prep_kernel<<<BIN_BLOCKS + CEMB_BLOCKS + CW_BLOCKS, 512, 0, stream>>>(
        src, dst, gcur, tmp, emb, embb, w1l, w1r, w2l, w2r, w1cat, w2cat);

    // layer 1 aggregation (bf16 gather): aggb = bf16(mean-gather(embb))
    agg_kernel<true><<<NBUK, 512, 0, stream>>>(gcur, tmp, embb, nullptr, nullptr, aggb);

    // fused MFMA layers: h = relu(cat(agg,emb)@w1cat^T + b1); {p2b, hzb} = h@{w2l,w2r}^T
    const int NT = (NN + 127) / 128;  // 782
    gemm_mfma_kernel<<<NT, 256, 0, stream>>>(aggb, embb, w1cat, b1, w2cat, p2b, hzb);

    // layer 2 aggregation + fuse: zb = bf16(mean-gather(p2b) + hz + b2)
    agg_kernel<false><<<NBUK, 512, 0, stream>>>(gcur, tmp, p2b, hzb, b2, zb);

    // decode
    decode_kernel<<<(NL * 16 + 255) / 256, 256, 0, stream>>>(eli, eli + NL, zb, out);
}